// Round 12
// baseline (328.244 us; speedup 1.0000x reference)
//
#include <hip/hip_runtime.h>
#include <hip/hip_bf16.h>
#include <cstddef>

#define B_    128
#define D_    2048
#define C_    16522
#define BETA_INV 20.0f      // 1/0.05
#define LSTRIDE 16528       // padded logits row stride (floats)

#define NTILES 1033         // ceil(C/16)
#define NPAIR  517          // ceil(NTILES/2): blocks, 2 adjacent tiles each

typedef __bf16 bf16;
typedef bf16  bf16x8 __attribute__((ext_vector_type(8)));
typedef bf16  bf16x4 __attribute__((ext_vector_type(4)));
typedef float f32x4  __attribute__((ext_vector_type(4)));

// ws layout (bytes):
//   logits : [0, 8462336)                128*16528*4
//   A_pack : [8462336, 8986624)          128*2048*2  bf16 fragment-ordered
#define WS_APACK_OFF 8462336

// ---------------------------------------------------------------------------
// pack_a: inputs [128,2048] fp32 -> bf16 in MFMA A-fragment order.
// frag f = mtile*64 + kstep; element tid = f*64 + lane (bf16x8 each).
// A[m = mtile*16 + (lane&15)][k = kstep*32 + (lane>>4)*8 + j]
// Also zeroes the loss accumulator (stream-ordered before tail's atomics).
// ---------------------------------------------------------------------------
__global__ __launch_bounds__(256) void pack_a(const float* __restrict__ inp,
                                              bf16* __restrict__ ap,
                                              float* __restrict__ out) {
  const int tid  = blockIdx.x * 256 + threadIdx.x;   // 0..32767
  if (tid == 0) out[0] = 0.f;
  const int lane = tid & 63;
  const int ks   = (tid >> 6) & 63;
  const int mt   = tid >> 12;
  const int row  = mt * 16 + (lane & 15);
  const int col  = ks * 32 + (lane >> 4) * 8;
  const f32x4 v0 = *(const f32x4*)(inp + row * D_ + col);
  const f32x4 v1 = *(const f32x4*)(inp + row * D_ + col + 4);
  bf16x8 b;
  b[0] = (bf16)v0[0]; b[1] = (bf16)v0[1]; b[2] = (bf16)v0[2]; b[3] = (bf16)v0[3];
  b[4] = (bf16)v1[0]; b[5] = (bf16)v1[1]; b[6] = (bf16)v1[2]; b[7] = (bf16)v1[3];
  ((bf16x8*)ap)[tid] = b;
}

static __device__ __forceinline__ bf16x4 cvt4(const f32x4 v) {
  bf16x4 h;
  h[0] = (bf16)v[0]; h[1] = (bf16)v[1]; h[2] = (bf16)v[2]; h[3] = (bf16)v[3];
  return h;
}

// ---------------------------------------------------------------------------
// gemm, round 12: TWO adjacent tiles per block with T14 stage-split.
// Timing model (rounds 5-11): per block, staging (HBM, ~2/3 of time) and
// k-loop (L2-bound A-pack reads, ~1/3) SERIALIZE, and 2 lockstep blocks/CU
// can't cover each other -> 94us floor across every intra-tile schedule.
// Fix: overlap ACROSS TILES WITHIN a block — issue tile-1's 16 HBM loads
// into registers BEFORE tile-0's k-loop; they land during the multi-us
// k-loop, so tile-1's staging collapses to ds_write+stores+barrier with no
// HBM-read wait. Grid 517 ~= 2.02 blocks/CU = ONE generation.
// Schedule: LOAD(t0) | DSWRITE+STOREOUT(t0) | bar | LOAD(t1) |
//           KLOOP(t0)+logits | bar | DSWRITE+STOREOUT(t1) | bar |
//           KLOOP(t1)+logits.
// Internals (swizzle, staging mapping, k-loop, store placement before
// barrier) are round-6 verbatim. T1 XCD swizzle removed (measured null).
// ---------------------------------------------------------------------------
__global__ __launch_bounds__(512, 4) void gemm_logits(
    const bf16*  __restrict__ ap,
    const float* __restrict__ em,
    float*       __restrict__ logits,
    float*       __restrict__ out_em)
{
  __shared__ bf16 sB[16 * 2048];       // 64 KB, swizzled layout

  const int t    = threadIdx.x;
  const int lane = t & 63;
  const int w    = t >> 6;             // wave id 0..7 == m-tile index
  const int ml   = lane & 15;
  const int quad = lane >> 4;

  const int swz   = (w & 7) << 4;      // staging swizzle key (rows w, w+8)
  const int rswz  = (ml & 7) << 4;     // read-side swizzle key
  const int rbase = (ml << 12) + (quad << 4);
  const bf16x8* apc = (const bf16x8*)ap + (size_t)(w * 64) * 64 + lane;

  f32x4 g[16];                         // staged rows w (g[0..7]) and w+8

  int nt = blockIdx.x * 2;             // first tile of the pair

  // initial load: tile nt
  {
    const int n0  = nt * 16;
    const int gr0 = (n0 + w     < C_) ? n0 + w     : C_ - 1;
    const int gr1 = (n0 + w + 8 < C_) ? n0 + w + 8 : C_ - 1;
    const f32x4* s0 = (const f32x4*)(em + (size_t)gr0 * D_);
    const f32x4* s1 = (const f32x4*)(em + (size_t)gr1 * D_);
    #pragma unroll
    for (int i = 0; i < 8; ++i) g[i]     = s0[lane + i * 64];
    #pragma unroll
    for (int i = 0; i < 8; ++i) g[8 + i] = s1[lane + i * 64];
  }

  #pragma unroll
  for (int p = 0; p < 2; ++p) {
    const int n0 = nt * 16;

    // ---- DSWRITE + copy-through STOREOUT (before barrier, round-6) ----
    #pragma unroll
    for (int i = 0; i < 8; ++i) {
      const int byte0 = (w << 12) + (lane << 3) + (i << 9);
      *(bf16x4*)((char*)sB + (byte0 ^ swz)) = cvt4(g[i]);
    }
    #pragma unroll
    for (int i = 0; i < 8; ++i) {
      const int byte1 = ((w + 8) << 12) + (lane << 3) + (i << 9);
      *(bf16x4*)((char*)sB + (byte1 ^ swz)) = cvt4(g[8 + i]);
    }
    if (n0 + w < C_) {
      f32x4* dst = (f32x4*)(out_em + (size_t)(n0 + w) * D_);
      #pragma unroll
      for (int i = 0; i < 8; ++i) dst[lane + i * 64] = g[i];
    }
    if (n0 + w + 8 < C_) {
      f32x4* dst = (f32x4*)(out_em + (size_t)(n0 + w + 8) * D_);
      #pragma unroll
      for (int i = 0; i < 8; ++i) dst[lane + i * 64] = g[8 + i];
    }
    __syncthreads();

    // ---- prefetch next tile's loads (in flight during the k-loop) -----
    const int  ntn  = nt + 1;
    const bool more = (p == 0) && (ntn < NTILES);
    if (more) {
      const int m0  = ntn * 16;
      const int gr0 = (m0 + w     < C_) ? m0 + w     : C_ - 1;
      const int gr1 = (m0 + w + 8 < C_) ? m0 + w + 8 : C_ - 1;
      const f32x4* s0 = (const f32x4*)(em + (size_t)gr0 * D_);
      const f32x4* s1 = (const f32x4*)(em + (size_t)gr1 * D_);
      #pragma unroll
      for (int i = 0; i < 8; ++i) g[i]     = s0[lane + i * 64];
      #pragma unroll
      for (int i = 0; i < 8; ++i) g[8 + i] = s1[lane + i * 64];
    }

    // ---- k-loop: 64 MFMA steps, B from LDS, A-frags L2-hot ------------
    f32x4 acc = {};
    const char* sb = (const char*)sB;
    #pragma unroll 16
    for (int ks = 0; ks < 64; ++ks) {
      const bf16x8 bfrag = *(const bf16x8*)(sb + ((rbase + (ks << 6)) ^ rswz));
      acc = __builtin_amdgcn_mfma_f32_16x16x32_bf16(apc[(size_t)ks * 64],
                                                    bfrag, acc, 0, 0, 0);
    }

    const int r = n0 + ml;
    if (r < C_) {
      #pragma unroll
      for (int reg = 0; reg < 4; ++reg) {
        const int row = w * 16 + quad * 4 + reg;
        logits[row * LSTRIDE + r] = acc[reg] * BETA_INV;
      }
    }

    if (!more) break;
    nt = ntn;
    __syncthreads();   // all waves done reading sB before it's overwritten
  }
}

// ---------------------------------------------------------------------------
// tail: fused row_loss (blocks 0..127, one block per sample row, full-row
// scan) and em_update (blocks 128..255). Branch is block-uniform.
// ---------------------------------------------------------------------------
__global__ __launch_bounds__(256) void tail(
    const float* __restrict__ logits,
    const int*   __restrict__ label,
    const float* __restrict__ inp,
    const float* __restrict__ em,
    const int*   __restrict__ epoch,
    float*       __restrict__ out,
    float*       __restrict__ out_em)
{
  __shared__ float rm[256], rs[256];
  __shared__ float cv[1536];
  __shared__ int   ci[1536];
  __shared__ float sly;
  __shared__ int   lbl[B_];
  __shared__ float red[4];

  const int t = threadIdx.x;

  if (blockIdx.x < B_) {
    // ---------------- row_loss: full row b, online lse + top-6 ----------
    const int b = blockIdx.x;
    const float* row = logits + b * LSTRIDE;
    const int y = label[b];

    float m = -INFINITY, s = 0.f, ly = -INFINITY;
    float tv[6]; int ti[6];
    #pragma unroll
    for (int q = 0; q < 6; ++q) { tv[q] = -INFINITY; ti[q] = -1; }

    for (int i = t; i < C_; i += 256) {
      const float v = row[i];
      if (v > m) { s = s * __expf(m - v) + 1.f; m = v; }
      else       { s += __expf(v - m); }
      if (i == y) ly = v;
      if (v > tv[5]) {
        tv[5] = v; ti[5] = i;
        #pragma unroll
        for (int q = 5; q > 0; --q)
          if (tv[q] > tv[q - 1]) {
            const float fv = tv[q]; tv[q] = tv[q - 1]; tv[q - 1] = fv;
            const int   fi = ti[q]; ti[q] = ti[q - 1]; ti[q - 1] = fi;
          }
      }
    }

    rm[t] = m; rs[t] = s;
    #pragma unroll
    for (int q = 0; q < 6; ++q) { cv[t * 6 + q] = tv[q]; ci[t * 6 + q] = ti[q]; }
    if (t == 0) sly = -INFINITY;
    __syncthreads();
    if (ly != -INFINITY) sly = ly;

    for (int off = 128; off >= 1; off >>= 1) {
      if (t < off) {
        const float m2 = rm[t + off], s2 = rs[t + off];
        const float M = fmaxf(rm[t], m2);
        rs[t] = rs[t] * __expf(rm[t] - M) + s2 * __expf(m2 - M);
        rm[t] = M;
      }
      __syncthreads();
    }

    if (t < 64) {   // wave 0: top-6 of 1536 candidates
      float otv[6]; int oti[6];
      for (int rr = 0; rr < 6; ++rr) {
        float bv = -INFINITY; int bi = -1, bs = -1;
        for (int u = 0; u < 24; ++u) {
          const int slot = t * 24 + u;
          const float v = cv[slot];
          if (v > bv) { bv = v; bi = ci[slot]; bs = slot; }
        }
        #pragma unroll
        for (int off = 32; off >= 1; off >>= 1) {
          const float ov = __shfl_down(bv, off);
          const int   oi = __shfl_down(bi, off);
          const int   os = __shfl_down(bs, off);
          if (ov > bv) { bv = ov; bi = oi; bs = os; }
        }
        bv = __shfl(bv, 0); bi = __shfl(bi, 0); bs = __shfl(bs, 0);
        if (bs >= t * 24 && bs < (t + 1) * 24) cv[bs] = -INFINITY;
        otv[rr] = bv; oti[rr] = bi;
      }
      if (t == 0) {
        const float lse = rm[0] + logf(rs[0]);
        float stop = 0.f; int intop = 0;
        #pragma unroll
        for (int q = 0; q < 6; ++q) {
          stop += otv[q];
          if (oti[q] == y) intop = 1;
        }
        const float lyv = sly;
        const float loss = intop ? (13.f * lse - lyv - 2.f * stop)
                                 : (15.f * lse - 3.f * lyv - 2.f * stop);
        atomicAdd(out, loss * (1.0f / 128.0f));
      }
    }
  } else {
    // ---------------- em_update: sample i = blockIdx.x - 128 ------------
    if (t < B_) lbl[t] = label[t];
    __syncthreads();

    const int i = blockIdx.x - B_;
    const int y = lbl[i];
    for (int j = 0; j < i; ++j)
      if (lbl[j] == y) return;          // uniform: all threads agree

    const float alpha = 0.01f * (float)epoch[0];
    const int lane = t & 63, wave = t >> 6;

    float rreg[8];
    #pragma unroll
    for (int u = 0; u < 8; ++u) rreg[u] = em[(size_t)y * D_ + t + u * 256];

    for (int j = i; j < B_; ++j) {
      if (lbl[j] != y) continue;        // uniform branch
      const float* x = inp + j * D_;
      float ss = 0.f;
      #pragma unroll
      for (int u = 0; u < 8; ++u) {
        rreg[u] = alpha * rreg[u] + (1.f - alpha) * x[t + u * 256];
        ss += rreg[u] * rreg[u];
      }
      #pragma unroll
      for (int off = 32; off >= 1; off >>= 1) ss += __shfl_down(ss, off);
      if (lane == 0) red[wave] = ss;
      __syncthreads();
      const float inv = 1.f / sqrtf(red[0] + red[1] + red[2] + red[3]);
      #pragma unroll
      for (int u = 0; u < 8; ++u) rreg[u] *= inv;
      __syncthreads();                  // red[] reused next chain step
    }

    #pragma unroll
    for (int u = 0; u < 8; ++u) out_em[(size_t)y * D_ + t + u * 256] = rreg[u];
  }
}

// ---------------------------------------------------------------------------
extern "C" void kernel_launch(void* const* d_in, const int* in_sizes, int n_in,
                              void* d_out, int out_size, void* d_ws, size_t ws_size,
                              hipStream_t stream) {
  const float* inp   = (const float*)d_in[0];
  const int*   label = (const int*)d_in[1];
  const float* em    = (const float*)d_in[2];
  const int*   epoch = (const int*)d_in[3];

  float* out    = (float*)d_out;
  float* out_em = out + 1;
  float* logits = (float*)d_ws;
  bf16*  apack  = (bf16*)((char*)d_ws + WS_APACK_OFF);

  pack_a      <<<dim3(128),   dim3(256), 0, stream>>>(inp, apack, out);
  gemm_logits <<<dim3(NPAIR), dim3(512), 0, stream>>>(apack, em, logits, out_em);
  tail        <<<dim3(2 * B_),dim3(256), 0, stream>>>(logits, label, inp, em,
                                                      epoch, out, out_em);
}

// Round 13
// 304.979 us; speedup vs baseline: 1.0763x; 1.0763x over previous
//
#include <hip/hip_runtime.h>
#include <hip/hip_bf16.h>
#include <cstddef>

#define B_    128
#define D_    2048
#define C_    16522
#define BETA_INV 20.0f      // 1/0.05
#define LSTRIDE 16528       // padded logits row stride (floats)

#define NTILES 1033         // ceil(C/16)

typedef __bf16 bf16;
typedef bf16  bf16x8 __attribute__((ext_vector_type(8)));
typedef bf16  bf16x4 __attribute__((ext_vector_type(4)));
typedef float f32x4  __attribute__((ext_vector_type(4)));

// ws layout (bytes):
//   logits : [0, 8462336)                128*16528*4
//   A_pack : [8462336, 8986624)          128*2048*2  bf16 fragment-ordered
#define WS_APACK_OFF 8462336

// ---------------------------------------------------------------------------
// pack_a: inputs [128,2048] fp32 -> bf16 in MFMA A-fragment order.
// frag f = mtile*64 + kstep; element tid = f*64 + lane (bf16x8 each).
// A[m = mtile*16 + (lane&15)][k = kstep*32 + (lane>>4)*8 + j]
// Also zeroes the loss accumulator (stream-ordered before tail's atomics).
// ---------------------------------------------------------------------------
__global__ __launch_bounds__(256) void pack_a(const float* __restrict__ inp,
                                              bf16* __restrict__ ap,
                                              float* __restrict__ out) {
  const int tid  = blockIdx.x * 256 + threadIdx.x;   // 0..32767
  if (tid == 0) out[0] = 0.f;
  const int lane = tid & 63;
  const int ks   = (tid >> 6) & 63;
  const int mt   = tid >> 12;
  const int row  = mt * 16 + (lane & 15);
  const int col  = ks * 32 + (lane >> 4) * 8;
  const f32x4 v0 = *(const f32x4*)(inp + row * D_ + col);
  const f32x4 v1 = *(const f32x4*)(inp + row * D_ + col + 4);
  bf16x8 b;
  b[0] = (bf16)v0[0]; b[1] = (bf16)v0[1]; b[2] = (bf16)v0[2]; b[3] = (bf16)v0[3];
  b[4] = (bf16)v1[0]; b[5] = (bf16)v1[1]; b[6] = (bf16)v1[2]; b[7] = (bf16)v1[3];
  ((bf16x8*)ap)[tid] = b;
}

static __device__ __forceinline__ bf16x4 cvt4(const f32x4 v) {
  bf16x4 h;
  h[0] = (bf16)v[0]; h[1] = (bf16)v[1]; h[2] = (bf16)v[2]; h[3] = (bf16)v[3];
  return h;
}

// ---------------------------------------------------------------------------
// gemm, round 13 = round 6 verbatim (BEST MEASURED: 94.5us gemm, 305.2us
// total). Single-barrier full-tile staging:
//  - wave w stages rows {w, w+8}: 8 coalesced f32x4 loads each (16 in
//    flight), fp32->bf16 convert, XOR-swizzled ds_write (byte^=(row&7)<<4,
//    same involution on read side).
//  - out_em copy-through from the same registers BEFORE the barrier
//    (deferring it or NT-storing it measured worse: rounds 9/2).
//  - ONE __syncthreads, then 64 MFMA k-steps; B from LDS, A-frags from
//    L2-hot A-pack; logits epilogue.
// Bracket established over rounds 5-12: barrier count {1,4,8}, pipeline
// depth {0,1,2}, store placement {pre-bar, post-kloop, NT}, block mix,
// K-split, XCD swizzle, cross-tile prefetch — all land 94-116us with this
// structure at the bottom. Remaining total is ~83us harness poison-fill
// (measured 6.5 TB/s fillBuffer) + small kernels + launch gaps.
// ---------------------------------------------------------------------------
__global__ __launch_bounds__(512, 4) void gemm_logits(
    const bf16*  __restrict__ ap,
    const float* __restrict__ em,
    float*       __restrict__ logits,
    float*       __restrict__ out_em)
{
  __shared__ bf16 sB[16 * 2048];       // 64 KB, swizzled layout

  const int t    = threadIdx.x;
  const int lane = t & 63;
  const int w    = t >> 6;             // wave id 0..7 == m-tile index
  const int ml   = lane & 15;
  const int quad = lane >> 4;
  const int n0   = blockIdx.x * 16;
  const int r    = n0 + ml;
  const bool valid = r < C_;

  // ---- staging + fused copy-through: wave w handles rows w and w+8 ----
  #pragma unroll
  for (int half = 0; half < 2; ++half) {
    const int row = w + half * 8;
    const int gr  = (n0 + row < C_) ? (n0 + row) : (C_ - 1);
    const f32x4* src = (const f32x4*)(em + (size_t)gr * D_);
    f32x4 g[8];
    #pragma unroll
    for (int i = 0; i < 8; ++i) g[i] = src[lane + i * 64];   // 8 loads in flight
    const int swz = (row & 7) << 4;
    #pragma unroll
    for (int i = 0; i < 8; ++i) {
      const int byte = (row << 12) + (lane << 3) + (i << 9); // row*4096+lane*8+i*512
      *(bf16x4*)((char*)sB + (byte ^ swz)) = cvt4(g[i]);
    }
    if (n0 + row < C_) {
      f32x4* dst = (f32x4*)(out_em + (size_t)(n0 + row) * D_);
      #pragma unroll
      for (int i = 0; i < 8; ++i) dst[lane + i * 64] = g[i];
    }
  }
  __syncthreads();   // the ONLY barrier

  // ---- k-loop: 64 MFMA steps, B from LDS, A-frags from L2-hot A-pack ---
  f32x4 acc = {};
  const bf16x8* apc = (const bf16x8*)ap + (size_t)(w * 64) * 64 + lane;
  const char* sb = (const char*)sB;
  const int rbase = (ml << 12) + (quad << 4);   // ml*4096 + quad*16
  const int rswz  = (ml & 7) << 4;
  #pragma unroll 16
  for (int ks = 0; ks < 64; ++ks) {
    const bf16x8 bfrag = *(const bf16x8*)(sb + ((rbase + (ks << 6)) ^ rswz));
    acc = __builtin_amdgcn_mfma_f32_16x16x32_bf16(apc[(size_t)ks * 64], bfrag,
                                                  acc, 0, 0, 0);
  }

  if (valid) {
    #pragma unroll
    for (int reg = 0; reg < 4; ++reg) {
      const int row = w * 16 + quad * 4 + reg;
      logits[row * LSTRIDE + r] = acc[reg] * BETA_INV;
    }
  }
}

// ---------------------------------------------------------------------------
// tail: fused row_loss (blocks 0..127, one block per sample row, full-row
// scan) and em_update (blocks 128..255). Branch is block-uniform.
// ---------------------------------------------------------------------------
__global__ __launch_bounds__(256) void tail(
    const float* __restrict__ logits,
    const int*   __restrict__ label,
    const float* __restrict__ inp,
    const float* __restrict__ em,
    const int*   __restrict__ epoch,
    float*       __restrict__ out,
    float*       __restrict__ out_em)
{
  __shared__ float rm[256], rs[256];
  __shared__ float cv[1536];
  __shared__ int   ci[1536];
  __shared__ float sly;
  __shared__ int   lbl[B_];
  __shared__ float red[4];

  const int t = threadIdx.x;

  if (blockIdx.x < B_) {
    // ---------------- row_loss: full row b, online lse + top-6 ----------
    const int b = blockIdx.x;
    const float* row = logits + b * LSTRIDE;
    const int y = label[b];

    float m = -INFINITY, s = 0.f, ly = -INFINITY;
    float tv[6]; int ti[6];
    #pragma unroll
    for (int q = 0; q < 6; ++q) { tv[q] = -INFINITY; ti[q] = -1; }

    for (int i = t; i < C_; i += 256) {
      const float v = row[i];
      if (v > m) { s = s * __expf(m - v) + 1.f; m = v; }
      else       { s += __expf(v - m); }
      if (i == y) ly = v;
      if (v > tv[5]) {
        tv[5] = v; ti[5] = i;
        #pragma unroll
        for (int q = 5; q > 0; --q)
          if (tv[q] > tv[q - 1]) {
            const float fv = tv[q]; tv[q] = tv[q - 1]; tv[q - 1] = fv;
            const int   fi = ti[q]; ti[q] = ti[q - 1]; ti[q - 1] = fi;
          }
      }
    }

    rm[t] = m; rs[t] = s;
    #pragma unroll
    for (int q = 0; q < 6; ++q) { cv[t * 6 + q] = tv[q]; ci[t * 6 + q] = ti[q]; }
    if (t == 0) sly = -INFINITY;
    __syncthreads();
    if (ly != -INFINITY) sly = ly;

    for (int off = 128; off >= 1; off >>= 1) {
      if (t < off) {
        const float m2 = rm[t + off], s2 = rs[t + off];
        const float M = fmaxf(rm[t], m2);
        rs[t] = rs[t] * __expf(rm[t] - M) + s2 * __expf(m2 - M);
        rm[t] = M;
      }
      __syncthreads();
    }

    if (t < 64) {   // wave 0: top-6 of 1536 candidates
      float otv[6]; int oti[6];
      for (int rr = 0; rr < 6; ++rr) {
        float bv = -INFINITY; int bi = -1, bs = -1;
        for (int u = 0; u < 24; ++u) {
          const int slot = t * 24 + u;
          const float v = cv[slot];
          if (v > bv) { bv = v; bi = ci[slot]; bs = slot; }
        }
        #pragma unroll
        for (int off = 32; off >= 1; off >>= 1) {
          const float ov = __shfl_down(bv, off);
          const int   oi = __shfl_down(bi, off);
          const int   os = __shfl_down(bs, off);
          if (ov > bv) { bv = ov; bi = oi; bs = os; }
        }
        bv = __shfl(bv, 0); bi = __shfl(bi, 0); bs = __shfl(bs, 0);
        if (bs >= t * 24 && bs < (t + 1) * 24) cv[bs] = -INFINITY;
        otv[rr] = bv; oti[rr] = bi;
      }
      if (t == 0) {
        const float lse = rm[0] + logf(rs[0]);
        float stop = 0.f; int intop = 0;
        #pragma unroll
        for (int q = 0; q < 6; ++q) {
          stop += otv[q];
          if (oti[q] == y) intop = 1;
        }
        const float lyv = sly;
        const float loss = intop ? (13.f * lse - lyv - 2.f * stop)
                                 : (15.f * lse - 3.f * lyv - 2.f * stop);
        atomicAdd(out, loss * (1.0f / 128.0f));
      }
    }
  } else {
    // ---------------- em_update: sample i = blockIdx.x - 128 ------------
    if (t < B_) lbl[t] = label[t];
    __syncthreads();

    const int i = blockIdx.x - B_;
    const int y = lbl[i];
    for (int j = 0; j < i; ++j)
      if (lbl[j] == y) return;          // uniform: all threads agree

    const float alpha = 0.01f * (float)epoch[0];
    const int lane = t & 63, wave = t >> 6;

    float rreg[8];
    #pragma unroll
    for (int u = 0; u < 8; ++u) rreg[u] = em[(size_t)y * D_ + t + u * 256];

    for (int j = i; j < B_; ++j) {
      if (lbl[j] != y) continue;        // uniform branch
      const float* x = inp + j * D_;
      float ss = 0.f;
      #pragma unroll
      for (int u = 0; u < 8; ++u) {
        rreg[u] = alpha * rreg[u] + (1.f - alpha) * x[t + u * 256];
        ss += rreg[u] * rreg[u];
      }
      #pragma unroll
      for (int off = 32; off >= 1; off >>= 1) ss += __shfl_down(ss, off);
      if (lane == 0) red[wave] = ss;
      __syncthreads();
      const float inv = 1.f / sqrtf(red[0] + red[1] + red[2] + red[3]);
      #pragma unroll
      for (int u = 0; u < 8; ++u) rreg[u] *= inv;
      __syncthreads();                  // red[] reused next chain step
    }

    #pragma unroll
    for (int u = 0; u < 8; ++u) out_em[(size_t)y * D_ + t + u * 256] = rreg[u];
  }
}

// ---------------------------------------------------------------------------
extern "C" void kernel_launch(void* const* d_in, const int* in_sizes, int n_in,
                              void* d_out, int out_size, void* d_ws, size_t ws_size,
                              hipStream_t stream) {
  const float* inp   = (const float*)d_in[0];
  const int*   label = (const int*)d_in[1];
  const float* em    = (const float*)d_in[2];
  const int*   epoch = (const int*)d_in[3];

  float* out    = (float*)d_out;
  float* out_em = out + 1;
  float* logits = (float*)d_ws;
  bf16*  apack  = (bf16*)((char*)d_ws + WS_APACK_OFF);

  pack_a      <<<dim3(128),    dim3(256), 0, stream>>>(inp, apack, out);
  gemm_logits <<<dim3(NTILES), dim3(512), 0, stream>>>(apack, em, logits, out_em);
  tail        <<<dim3(2 * B_), dim3(256), 0, stream>>>(logits, label, inp, em,
                                                       epoch, out, out_em);
}